// Round 1
// baseline (284.542 us; speedup 1.0000x reference)
//
#include <hip/hip_runtime.h>
#include <cfloat>

#define NN 1024
#define DD 64
#define DDP 32

// ---- ws layout (bytes) ----
// 0x000000  mask    uint8[NN*NN]   (1 MiB)
// 0x100000  indeg   int[NN]
// 0x101000  overlap int[NN]
// 0x102000  maxbits unsigned[2]
// 0x103000  c       int[NN]
// 0x104000  mu      float[64]
// 0x104100  scale   float[64]
// 0x200000  x       float[NN*64]
// 0x240000  y       float[NN*64]
// total 0x280000 = 2.5 MiB

__global__ __launch_bounds__(256) void gcn_dist_max(const float* __restrict__ XH,
                                                    const float* __restrict__ XP,
                                                    unsigned* __restrict__ maxbits) {
    const int i = blockIdx.x >> 2;
    const int j = ((blockIdx.x & 3) << 8) | threadIdx.x;
    __shared__ float4 shi[16];
    __shared__ float4 spi[8];
    if (threadIdx.x < 16) shi[threadIdx.x] = ((const float4*)(XH + i * 64))[threadIdx.x];
    else if (threadIdx.x < 24) spi[threadIdx.x - 16] = ((const float4*)(XP + i * 32))[threadIdx.x - 16];
    __syncthreads();
    const float4* xr = (const float4*)(XH + j * 64);
    float dh = 0.f;
#pragma unroll
    for (int d = 0; d < 16; ++d) {
        float4 a = shi[d], b = xr[d];
        float dx = a.x - b.x, dy = a.y - b.y, dz = a.z - b.z, dw = a.w - b.w;
        dh += dx * dx + dy * dy + dz * dz + dw * dw;
    }
    const float4* pr = (const float4*)(XP + j * 32);
    float dp = 0.f;
#pragma unroll
    for (int d = 0; d < 8; ++d) {
        float4 a = spi[d], b = pr[d];
        float dx = a.x - b.x, dy = a.y - b.y, dz = a.z - b.z, dw = a.w - b.w;
        dp += dx * dx + dy * dy + dz * dz + dw * dw;
    }
    __shared__ float rh[256], rp[256];
    rh[threadIdx.x] = dh; rp[threadIdx.x] = dp;
    __syncthreads();
    for (int s = 128; s > 0; s >>= 1) {
        if (threadIdx.x < s) {
            rh[threadIdx.x] = fmaxf(rh[threadIdx.x], rh[threadIdx.x + s]);
            rp[threadIdx.x] = fmaxf(rp[threadIdx.x], rp[threadIdx.x + s]);
        }
        __syncthreads();
    }
    if (threadIdx.x == 0) {
        atomicMax(&maxbits[0], __float_as_uint(sqrtf(rh[0])));
        atomicMax(&maxbits[1], __float_as_uint(sqrtf(rp[0])));
    }
}

__global__ __launch_bounds__(256) void gcn_topk(const float* __restrict__ XH,
                                                const float* __restrict__ XP,
                                                const unsigned* __restrict__ maxbits,
                                                const int* __restrict__ kptr,
                                                unsigned char* __restrict__ mask,
                                                int* __restrict__ indeg) {
    const int i = blockIdx.x;
    const int tid = threadIdx.x;
    __shared__ float4 shi[16];
    __shared__ float4 spi[8];
    __shared__ float ww[NN];
    __shared__ float rv[256];
    __shared__ int ri[256];
    if (tid < 16) shi[tid] = ((const float4*)(XH + i * 64))[tid];
    else if (tid < 24) spi[tid - 16] = ((const float4*)(XP + i * 32))[tid - 16];
    __syncthreads();
    const float cH = -0.5f / __uint_as_float(maxbits[0]);
    const float cP = -1.0f / __uint_as_float(maxbits[1]);
    for (int j = tid; j < NN; j += 256) {
        const float4* xr = (const float4*)(XH + j * 64);
        float dh = 0.f;
#pragma unroll
        for (int d = 0; d < 16; ++d) {
            float4 a = shi[d], b = xr[d];
            float dx = a.x - b.x, dy = a.y - b.y, dz = a.z - b.z, dw = a.w - b.w;
            dh += dx * dx + dy * dy + dz * dz + dw * dw;
        }
        const float4* pr = (const float4*)(XP + j * 32);
        float dp = 0.f;
#pragma unroll
        for (int d = 0; d < 8; ++d) {
            float4 a = spi[d], b = pr[d];
            float dx = a.x - b.x, dy = a.y - b.y, dz = a.z - b.z, dw = a.w - b.w;
            dp += dx * dx + dy * dy + dz * dz + dw * dw;
        }
        ww[j] = expf(sqrtf(dh) * cH) + 0.2f * expf(sqrtf(dp) * cP);
    }
    __syncthreads();
    const int K = *kptr;
    for (int t = 0; t < K; ++t) {
        float bv = -FLT_MAX; int bi = NN;
        for (int j = tid; j < NN; j += 256) {
            float v = ww[j];
            if (v > bv) { bv = v; bi = j; }
        }
        rv[tid] = bv; ri[tid] = bi;
        __syncthreads();
        for (int s = 128; s > 0; s >>= 1) {
            if (tid < s) {
                float v2 = rv[tid + s]; int i2 = ri[tid + s];
                if (v2 > rv[tid] || (v2 == rv[tid] && i2 < ri[tid])) { rv[tid] = v2; ri[tid] = i2; }
            }
            __syncthreads();
        }
        if (tid == 0) {
            int b = ri[0];
            mask[(size_t)i * NN + b] = 1;
            atomicAdd(&indeg[b], 1);
            ww[b] = -FLT_MAX;
        }
        __syncthreads();
    }
}

__global__ __launch_bounds__(256) void gcn_overlap(const unsigned char* __restrict__ mask,
                                                   int* __restrict__ overlap) {
    const int gid = blockIdx.x * 256 + threadIdx.x;
    const int i = gid >> 10, j = gid & 1023;
    if (mask[gid] && mask[(size_t)j * NN + i]) atomicAdd(&overlap[j], 1);
}

__global__ __launch_bounds__(256) void gcn_degree(const int* __restrict__ indeg,
                                                  const int* __restrict__ overlap,
                                                  const int* __restrict__ kptr,
                                                  int* __restrict__ cdeg) {
    const int j = blockIdx.x * 256 + threadIdx.x;
    if (j < NN) cdeg[j] = *kptr + indeg[j] - overlap[j];
}

__global__ __launch_bounds__(64) void gcn_xy(const float* __restrict__ XX,
                                             const float* __restrict__ W,
                                             const float* __restrict__ psi_w,
                                             float* __restrict__ x,
                                             float* __restrict__ y) {
    const int i = blockIdx.x;
    const int e = threadIdx.x;  // 64
    __shared__ float xin[64], xs[64];
    xin[e] = XX[i * 64 + e];
    __syncthreads();
    float acc = 0.f;
#pragma unroll
    for (int d = 0; d < 64; ++d) acc += xin[d] * W[d * 64 + e];
    xs[e] = acc;
    x[i * 64 + e] = acc;
    __syncthreads();
    float acc2 = 0.f;
    const float* pw = psi_w + e * 64;
#pragma unroll
    for (int d = 0; d < 64; ++d) acc2 += xs[d] * pw[d];
    y[i * 64 + e] = acc2;
}

__global__ __launch_bounds__(256) void gcn_mu(const float* __restrict__ y,
                                              const int* __restrict__ cdeg,
                                              const float* __restrict__ psi_b,
                                              float* __restrict__ mu) {
    const int e = blockIdx.x;
    const int tid = threadIdx.x;
    __shared__ double red[256];
    double s = 0.0;
    for (int j = tid; j < NN; j += 256)
        s += (double)(NN + cdeg[j]) * (double)y[j * 64 + e];
    red[tid] = s;
    __syncthreads();
    for (int k = 128; k > 0; k >>= 1) {
        if (tid < k) red[tid] += red[tid + k];
        __syncthreads();
    }
    if (tid == 0) mu[e] = (float)(red[0] / 1048576.0) + psi_b[e];
}

__global__ __launch_bounds__(256) void gcn_var(const float* __restrict__ y,
                                               const int* __restrict__ cdeg,
                                               const float* __restrict__ psi_b,
                                               const float* __restrict__ gamma,
                                               const float* __restrict__ mu,
                                               float* __restrict__ scale) {
    const int e = blockIdx.x;
    const int tid = threadIdx.x;
    __shared__ double red[256];
    const float m = mu[e], b = psi_b[e];
    double s = 0.0;
    for (int j = tid; j < NN; j += 256) {
        float t = y[j * 64 + e];
        float a1 = t + b - m;
        float a2 = 2.f * t + b - m;
        int cj = cdeg[j];
        s += (double)(NN - cj) * (double)a1 * (double)a1
           + (double)cj * (double)a2 * (double)a2;
    }
    red[tid] = s;
    __syncthreads();
    for (int k = 128; k > 0; k >>= 1) {
        if (tid < k) red[tid] += red[tid + k];
        __syncthreads();
    }
    if (tid == 0) {
        double var = red[0] / 1048576.0;
        scale[e] = (float)(1.0 / sqrt(var + 1e-5)) * gamma[e];
    }
}

__global__ __launch_bounds__(64) void gcn_out(const float* __restrict__ x,
                                              const float* __restrict__ y,
                                              const int* __restrict__ cdeg,
                                              const float* __restrict__ psi_b,
                                              const float* __restrict__ beta,
                                              const float* __restrict__ mu,
                                              const float* __restrict__ scale,
                                              const float* __restrict__ bias,
                                              const float* __restrict__ XP,
                                              float* __restrict__ out) {
    const int j = blockIdx.x;
    const int e = threadIdx.x;  // 64
    float t = y[j * 64 + e];
    float z = (2.f * t + psi_b[e] - mu[e]) * scale[e] + beta[e];
    float s = 1.f / (1.f + expf(-z));
    float val = x[j * 64 + e] * ((float)(cdeg[j] - 1) * s + 1.f) + bias[e];
    out[j * 64 + e] = val;                  // output 0: out[:, :64]
    out[98304 + j * 64 + e] = val;          // output 2: out
    if (e < 32) out[65536 + j * 32 + e] = XP[j * 32 + e];  // output 1: XP passthrough
}

extern "C" void kernel_launch(void* const* d_in, const int* in_sizes, int n_in,
                              void* d_out, int out_size, void* d_ws, size_t ws_size,
                              hipStream_t stream) {
    const float* XH    = (const float*)d_in[0];
    const float* XP    = (const float*)d_in[1];
    const float* XX    = (const float*)d_in[2];
    const int*   Kp    = (const int*)d_in[3];
    const float* W     = (const float*)d_in[4];
    const float* bias  = (const float*)d_in[5];
    const float* psi_w = (const float*)d_in[6];
    const float* psi_b = (const float*)d_in[7];
    const float* gamma = (const float*)d_in[8];
    const float* beta  = (const float*)d_in[9];
    float* out = (float*)d_out;
    char* ws = (char*)d_ws;

    unsigned char* mask = (unsigned char*)ws;
    int* indeg    = (int*)(ws + 0x100000);
    int* overlap  = (int*)(ws + 0x101000);
    unsigned* maxbits = (unsigned*)(ws + 0x102000);
    int* cdeg     = (int*)(ws + 0x103000);
    float* mu     = (float*)(ws + 0x104000);
    float* scale  = (float*)(ws + 0x104100);
    float* x      = (float*)(ws + 0x200000);
    float* y      = (float*)(ws + 0x240000);

    // zero: mask + indeg + overlap + maxbits (ws is poisoned 0xAA before every call)
    hipMemsetAsync(ws, 0, 0x102100, stream);

    gcn_dist_max<<<dim3(4096), dim3(256), 0, stream>>>(XH, XP, maxbits);
    gcn_topk<<<dim3(1024), dim3(256), 0, stream>>>(XH, XP, maxbits, Kp, mask, indeg);
    gcn_overlap<<<dim3(4096), dim3(256), 0, stream>>>(mask, overlap);
    gcn_degree<<<dim3(4), dim3(256), 0, stream>>>(indeg, overlap, Kp, cdeg);
    gcn_xy<<<dim3(1024), dim3(64), 0, stream>>>(XX, W, psi_w, x, y);
    gcn_mu<<<dim3(64), dim3(256), 0, stream>>>(y, cdeg, psi_b, mu);
    gcn_var<<<dim3(64), dim3(256), 0, stream>>>(y, cdeg, psi_b, gamma, mu, scale);
    gcn_out<<<dim3(1024), dim3(64), 0, stream>>>(x, y, cdeg, psi_b, beta, mu, scale, bias, XP, out);
}

// Round 2
// 165.416 us; speedup vs baseline: 1.7202x; 1.7202x over previous
//
#include <hip/hip_runtime.h>
#include <cfloat>

#define NN 1024

// ---- ws layout (bytes) ----
// 0x000000  mask    uint8[NN*NN]   (1 MiB)
// 0x100000  indeg   int[NN]
// 0x101000  overlap int[NN]
// 0x102000  maxbits: [0]=max dh (sq), at +0x80: max dp (sq)  (separate lines)
// 0x103000  cdeg    int[NN]
// 0x104000  mu      float[64]
// 0x104100  scale   float[64]
// 0x200000  x       float[NN*64]
// 0x240000  y       float[NN*64]
// 0x280000  XHT     float[64][1024]  (256 KiB)
// 0x2C0000  XPT     float[32][1024]  (128 KiB)
// end 0x2E0000 (~2.9 MiB)

__global__ __launch_bounds__(256) void gcn_transpose(const float* __restrict__ XH,
                                                     const float* __restrict__ XP,
                                                     float* __restrict__ XHT,
                                                     float* __restrict__ XPT) {
    const int b = blockIdx.x;        // 16 blocks, 64 rows each
    const int j0 = b * 64;
    const int tid = threadIdx.x;
    __shared__ float th[64][65];     // [d][j_local]
    __shared__ float tp[32][65];
#pragma unroll
    for (int it = 0; it < 16; ++it) {
        int idx = it * 256 + tid;
        int jl = idx >> 6, d = idx & 63;
        th[d][jl] = XH[(j0 + jl) * 64 + d];
    }
#pragma unroll
    for (int it = 0; it < 8; ++it) {
        int idx = it * 256 + tid;
        int jl = idx >> 5, d = idx & 31;
        tp[d][jl] = XP[(j0 + jl) * 32 + d];
    }
    __syncthreads();
#pragma unroll
    for (int it = 0; it < 16; ++it) {
        int idx = it * 256 + tid;
        int d = idx >> 6, jl = idx & 63;
        XHT[d * NN + j0 + jl] = th[d][jl];
    }
#pragma unroll
    for (int it = 0; it < 8; ++it) {
        int idx = it * 256 + tid;
        int d = idx >> 6, jl = idx & 63;
        XPT[d * NN + j0 + jl] = tp[d][jl];
    }
}

// 256 blocks; block b handles i-rows 4b..4b+3 against ALL j (4 j's per thread via float4).
__global__ __launch_bounds__(256) void gcn_dist(const float* __restrict__ XH,
                                                const float* __restrict__ XP,
                                                const float* __restrict__ XHT,
                                                const float* __restrict__ XPT,
                                                unsigned* __restrict__ maxbits) {
    const int i0 = blockIdx.x * 4;
    const int tid = threadIdx.x;
    __shared__ float shi[4][64];
    __shared__ float spi[4][32];
    shi[tid >> 6][tid & 63] = XH[(i0 + (tid >> 6)) * 64 + (tid & 63)];
    if (tid < 128) spi[tid >> 5][tid & 31] = XP[(i0 + (tid >> 5)) * 32 + (tid & 31)];
    __syncthreads();
    const float4* XHTv = (const float4*)XHT;
    const float4* XPTv = (const float4*)XPT;
    float4 dh[4], dp[4];
#pragma unroll
    for (int r = 0; r < 4; ++r) { dh[r] = make_float4(0, 0, 0, 0); dp[r] = make_float4(0, 0, 0, 0); }
#pragma unroll 8
    for (int d = 0; d < 64; ++d) {
        float4 h = XHTv[d * 256 + tid];
#pragma unroll
        for (int r = 0; r < 4; ++r) {
            float s = shi[r][d];
            float tx = h.x - s, ty = h.y - s, tz = h.z - s, tw = h.w - s;
            dh[r].x += tx * tx; dh[r].y += ty * ty; dh[r].z += tz * tz; dh[r].w += tw * tw;
        }
    }
#pragma unroll 8
    for (int d = 0; d < 32; ++d) {
        float4 p = XPTv[d * 256 + tid];
#pragma unroll
        for (int r = 0; r < 4; ++r) {
            float s = spi[r][d];
            float tx = p.x - s, ty = p.y - s, tz = p.z - s, tw = p.w - s;
            dp[r].x += tx * tx; dp[r].y += ty * ty; dp[r].z += tz * tz; dp[r].w += tw * tw;
        }
    }
    float mh = 0.f, mp = 0.f;
#pragma unroll
    for (int r = 0; r < 4; ++r) {
        mh = fmaxf(mh, fmaxf(fmaxf(dh[r].x, dh[r].y), fmaxf(dh[r].z, dh[r].w)));
        mp = fmaxf(mp, fmaxf(fmaxf(dp[r].x, dp[r].y), fmaxf(dp[r].z, dp[r].w)));
    }
#pragma unroll
    for (int m = 1; m < 64; m <<= 1) {
        mh = fmaxf(mh, __shfl_xor(mh, m));
        mp = fmaxf(mp, __shfl_xor(mp, m));
    }
    __shared__ float wmx[4][2];
    if ((tid & 63) == 0) { wmx[tid >> 6][0] = mh; wmx[tid >> 6][1] = mp; }
    __syncthreads();
    if (tid == 0) {
        float a = fmaxf(fmaxf(wmx[0][0], wmx[1][0]), fmaxf(wmx[2][0], wmx[3][0]));
        float b = fmaxf(fmaxf(wmx[0][1], wmx[1][1]), fmaxf(wmx[2][1], wmx[3][1]));
        atomicMax(&maxbits[0], __float_as_uint(a));
        atomicMax(&maxbits[32], __float_as_uint(b));
    }
}

// 256 blocks x 256 threads; wave w handles row i = 4*blockIdx.x + w. Barrier-free top-K.
__global__ __launch_bounds__(256) void gcn_topk(const float* __restrict__ XH,
                                                const float* __restrict__ XP,
                                                const float* __restrict__ XHT,
                                                const float* __restrict__ XPT,
                                                const unsigned* __restrict__ maxbits,
                                                const int* __restrict__ kptr,
                                                unsigned char* __restrict__ mask,
                                                int* __restrict__ indeg) {
    const int i0 = blockIdx.x * 4;
    const int tid = threadIdx.x;
    const int w = tid >> 6;          // wave id 0..3
    const int lane = tid & 63;
    const int i = i0 + w;
    __shared__ float shi[4][64];
    __shared__ float spi[4][32];
    shi[tid >> 6][tid & 63] = XH[(i0 + (tid >> 6)) * 64 + (tid & 63)];
    if (tid < 128) spi[tid >> 5][tid & 31] = XP[(i0 + (tid >> 5)) * 32 + (tid & 31)];
    __syncthreads();
    const float cH = -0.5f / sqrtf(__uint_as_float(maxbits[0]));
    const float cP = -1.0f / sqrtf(__uint_as_float(maxbits[32]));
    const float4* XHTv = (const float4*)XHT;
    const float4* XPTv = (const float4*)XPT;
    float ww[16];
#pragma unroll
    for (int s = 0; s < 4; ++s) {   // j = s*256 + lane*4 + q
        float4 dh = make_float4(0, 0, 0, 0), dp = make_float4(0, 0, 0, 0);
#pragma unroll 8
        for (int d = 0; d < 64; ++d) {
            float4 h = XHTv[d * 256 + s * 64 + lane];
            float c = shi[w][d];
            float tx = h.x - c, ty = h.y - c, tz = h.z - c, tw = h.w - c;
            dh.x += tx * tx; dh.y += ty * ty; dh.z += tz * tz; dh.w += tw * tw;
        }
#pragma unroll 8
        for (int d = 0; d < 32; ++d) {
            float4 p = XPTv[d * 256 + s * 64 + lane];
            float c = spi[w][d];
            float tx = p.x - c, ty = p.y - c, tz = p.z - c, tw = p.w - c;
            dp.x += tx * tx; dp.y += ty * ty; dp.z += tz * tz; dp.w += tw * tw;
        }
        ww[s * 4 + 0] = expf(sqrtf(dh.x) * cH) + 0.2f * expf(sqrtf(dp.x) * cP);
        ww[s * 4 + 1] = expf(sqrtf(dh.y) * cH) + 0.2f * expf(sqrtf(dp.y) * cP);
        ww[s * 4 + 2] = expf(sqrtf(dh.z) * cH) + 0.2f * expf(sqrtf(dp.z) * cP);
        ww[s * 4 + 3] = expf(sqrtf(dh.w) * cH) + 0.2f * expf(sqrtf(dp.w) * cP);
    }
    const int K = *kptr;
    int jsave = 0;
    for (int t = 0; t < K; ++t) {
        // local scan over 16 slots; j = (v>>2)*256 + lane*4 + (v&3)
        float bv = -FLT_MAX; int bj = NN;
#pragma unroll
        for (int v = 0; v < 16; ++v) {
            int j = ((v >> 2) << 8) | (lane << 2) | (v & 3);
            float val = ww[v];
            if (val > bv || (val == bv && j < bj)) { bv = val; bj = j; }
        }
#pragma unroll
        for (int m = 1; m < 64; m <<= 1) {
            float ov = __shfl_xor(bv, m);
            int oj = __shfl_xor(bj, m);
            if (ov > bv || (ov == bv && oj < bj)) { bv = ov; bj = oj; }
        }
        if ((int)lane == t) jsave = bj;
        if (((bj >> 2) & 63) == lane) {
            int slot = ((bj >> 8) << 2) | (bj & 3);
#pragma unroll
            for (int v = 0; v < 16; ++v)
                if (v == slot) ww[v] = -FLT_MAX;
        }
    }
    if (lane < K) {
        mask[(size_t)i * NN + jsave] = 1;
        atomicAdd(&indeg[jsave], 1);
    }
}

__global__ __launch_bounds__(256) void gcn_overlap(const unsigned char* __restrict__ mask,
                                                   int* __restrict__ overlap) {
    const int gid = blockIdx.x * 256 + threadIdx.x;
    const int i = gid >> 10, j = gid & 1023;
    if (mask[gid] && mask[(size_t)j * NN + i]) atomicAdd(&overlap[j], 1);
}

__global__ __launch_bounds__(256) void gcn_degree(const int* __restrict__ indeg,
                                                  const int* __restrict__ overlap,
                                                  const int* __restrict__ kptr,
                                                  int* __restrict__ cdeg) {
    const int j = blockIdx.x * 256 + threadIdx.x;
    if (j < NN) cdeg[j] = *kptr + indeg[j] - overlap[j];
}

__global__ __launch_bounds__(64) void gcn_xy(const float* __restrict__ XX,
                                             const float* __restrict__ W,
                                             const float* __restrict__ psi_w,
                                             float* __restrict__ x,
                                             float* __restrict__ y) {
    const int i = blockIdx.x;
    const int e = threadIdx.x;  // 64
    __shared__ float xin[64], xs[64];
    xin[e] = XX[i * 64 + e];
    __syncthreads();
    float acc = 0.f;
#pragma unroll
    for (int d = 0; d < 64; ++d) acc += xin[d] * W[d * 64 + e];
    xs[e] = acc;
    x[i * 64 + e] = acc;
    __syncthreads();
    float acc2 = 0.f;
    const float* pw = psi_w + e * 64;
#pragma unroll
    for (int d = 0; d < 64; ++d) acc2 += xs[d] * pw[d];
    y[i * 64 + e] = acc2;
}

__global__ __launch_bounds__(256) void gcn_mu(const float* __restrict__ y,
                                              const int* __restrict__ cdeg,
                                              const float* __restrict__ psi_b,
                                              float* __restrict__ mu) {
    const int e = blockIdx.x;
    const int tid = threadIdx.x;
    __shared__ double red[256];
    double s = 0.0;
    for (int j = tid; j < NN; j += 256)
        s += (double)(NN + cdeg[j]) * (double)y[j * 64 + e];
    red[tid] = s;
    __syncthreads();
    for (int k = 128; k > 0; k >>= 1) {
        if (tid < k) red[tid] += red[tid + k];
        __syncthreads();
    }
    if (tid == 0) mu[e] = (float)(red[0] / 1048576.0) + psi_b[e];
}

__global__ __launch_bounds__(256) void gcn_var(const float* __restrict__ y,
                                               const int* __restrict__ cdeg,
                                               const float* __restrict__ psi_b,
                                               const float* __restrict__ gamma,
                                               const float* __restrict__ mu,
                                               float* __restrict__ scale) {
    const int e = blockIdx.x;
    const int tid = threadIdx.x;
    __shared__ double red[256];
    const float m = mu[e], b = psi_b[e];
    double s = 0.0;
    for (int j = tid; j < NN; j += 256) {
        float t = y[j * 64 + e];
        float a1 = t + b - m;
        float a2 = 2.f * t + b - m;
        int cj = cdeg[j];
        s += (double)(NN - cj) * (double)a1 * (double)a1
           + (double)cj * (double)a2 * (double)a2;
    }
    red[tid] = s;
    __syncthreads();
    for (int k = 128; k > 0; k >>= 1) {
        if (tid < k) red[tid] += red[tid + k];
        __syncthreads();
    }
    if (tid == 0) {
        double var = red[0] / 1048576.0;
        scale[e] = (float)(1.0 / sqrt(var + 1e-5)) * gamma[e];
    }
}

__global__ __launch_bounds__(64) void gcn_out(const float* __restrict__ x,
                                              const float* __restrict__ y,
                                              const int* __restrict__ cdeg,
                                              const float* __restrict__ psi_b,
                                              const float* __restrict__ beta,
                                              const float* __restrict__ mu,
                                              const float* __restrict__ scale,
                                              const float* __restrict__ bias,
                                              const float* __restrict__ XP,
                                              float* __restrict__ out) {
    const int j = blockIdx.x;
    const int e = threadIdx.x;  // 64
    float t = y[j * 64 + e];
    float z = (2.f * t + psi_b[e] - mu[e]) * scale[e] + beta[e];
    float s = 1.f / (1.f + expf(-z));
    float val = x[j * 64 + e] * ((float)(cdeg[j] - 1) * s + 1.f) + bias[e];
    out[j * 64 + e] = val;                  // output 0: out[:, :64]
    out[98304 + j * 64 + e] = val;          // output 2: out
    if (e < 32) out[65536 + j * 32 + e] = XP[j * 32 + e];  // output 1: XP passthrough
}

extern "C" void kernel_launch(void* const* d_in, const int* in_sizes, int n_in,
                              void* d_out, int out_size, void* d_ws, size_t ws_size,
                              hipStream_t stream) {
    const float* XH    = (const float*)d_in[0];
    const float* XP    = (const float*)d_in[1];
    const float* XX    = (const float*)d_in[2];
    const int*   Kp    = (const int*)d_in[3];
    const float* W     = (const float*)d_in[4];
    const float* bias  = (const float*)d_in[5];
    const float* psi_w = (const float*)d_in[6];
    const float* psi_b = (const float*)d_in[7];
    const float* gamma = (const float*)d_in[8];
    const float* beta  = (const float*)d_in[9];
    float* out = (float*)d_out;
    char* ws = (char*)d_ws;

    unsigned char* mask = (unsigned char*)ws;
    int* indeg        = (int*)(ws + 0x100000);
    int* overlap      = (int*)(ws + 0x101000);
    unsigned* maxbits = (unsigned*)(ws + 0x102000);
    int* cdeg         = (int*)(ws + 0x103000);
    float* mu         = (float*)(ws + 0x104000);
    float* scale      = (float*)(ws + 0x104100);
    float* x          = (float*)(ws + 0x200000);
    float* y          = (float*)(ws + 0x240000);
    float* XHT        = (float*)(ws + 0x280000);
    float* XPT        = (float*)(ws + 0x2C0000);

    // zero: mask + indeg + overlap + maxbits
    hipMemsetAsync(ws, 0, 0x102200, stream);

    gcn_transpose<<<dim3(16), dim3(256), 0, stream>>>(XH, XP, XHT, XPT);
    gcn_dist<<<dim3(256), dim3(256), 0, stream>>>(XH, XP, XHT, XPT, maxbits);
    gcn_topk<<<dim3(256), dim3(256), 0, stream>>>(XH, XP, XHT, XPT, maxbits, Kp, mask, indeg);
    gcn_overlap<<<dim3(4096), dim3(256), 0, stream>>>(mask, overlap);
    gcn_degree<<<dim3(4), dim3(256), 0, stream>>>(indeg, overlap, Kp, cdeg);
    gcn_xy<<<dim3(1024), dim3(64), 0, stream>>>(XX, W, psi_w, x, y);
    gcn_mu<<<dim3(64), dim3(256), 0, stream>>>(y, cdeg, psi_b, mu);
    gcn_var<<<dim3(64), dim3(256), 0, stream>>>(y, cdeg, psi_b, gamma, mu, scale);
    gcn_out<<<dim3(1024), dim3(64), 0, stream>>>(x, y, cdeg, psi_b, beta, mu, scale, bias, XP, out);
}

// Round 3
// 142.713 us; speedup vs baseline: 1.9938x; 1.1591x over previous
//
#include <hip/hip_runtime.h>
#include <hip/hip_fp16.h>
#include <cfloat>

#define NN 1024

// ---- ws layout (bytes) ----
// 0x000000 dist   half2[1024*1024]  {sqrt(dh), sqrt(dp)}  (4 MiB)
// 0x400000 XHT    float[64][1024]   (256 KiB)
// 0x440000 XPT    float[32][1024]   (128 KiB)
// 0x460000 eidx   int[1024][16]     (64 KiB)   memset 0xFF
// 0x470000 indeg  int[1024]
// 0x471000 overlap int[1024]
// 0x472000 maxbits unsigned: [0]=max dh^2, [32]=max dp^2
// 0x473000 cdeg   int[1024]
// 0x474000 m0     float[64]
// 0x474200 scale  float[64]
// 0x480000 x      float[1024*64]    (256 KiB)
// 0x4C0000 y      float[1024*64]    (256 KiB)
// end 0x500000 (5 MiB)

__global__ __launch_bounds__(256) void gcn_transpose(const float* __restrict__ XH,
                                                     const float* __restrict__ XP,
                                                     float* __restrict__ XHT,
                                                     float* __restrict__ XPT) {
    const int j0 = blockIdx.x * 64;  // 16 blocks, 64 rows each
    const int tid = threadIdx.x;
    __shared__ float th[64][65];
    __shared__ float tp[32][65];
#pragma unroll
    for (int it = 0; it < 16; ++it) {
        int idx = it * 256 + tid;
        int jl = idx >> 6, d = idx & 63;
        th[d][jl] = XH[(j0 + jl) * 64 + d];
    }
#pragma unroll
    for (int it = 0; it < 8; ++it) {
        int idx = it * 256 + tid;
        int jl = idx >> 5, d = idx & 31;
        tp[d][jl] = XP[(j0 + jl) * 32 + d];
    }
    __syncthreads();
#pragma unroll
    for (int it = 0; it < 16; ++it) {
        int idx = it * 256 + tid;
        int d = idx >> 6, jl = idx & 63;
        XHT[d * NN + j0 + jl] = th[d][jl];
    }
#pragma unroll
    for (int it = 0; it < 8; ++it) {
        int idx = it * 256 + tid;
        int d = idx >> 6, jl = idx & 63;
        XPT[d * NN + j0 + jl] = tp[d][jl];
    }
}

// 1024 blocks: block = (i-group of 4) x (j-chunk of 256). 16 waves/CU.
__global__ __launch_bounds__(256) void gcn_dist(const float* __restrict__ XH,
                                                const float* __restrict__ XP,
                                                const float* __restrict__ XHT,
                                                const float* __restrict__ XPT,
                                                __half2* __restrict__ dist,
                                                unsigned* __restrict__ maxbits) {
    const int b = blockIdx.x;
    const int i0 = (b >> 2) * 4;
    const int j = (b & 3) * 256 + threadIdx.x;
    const int tid = threadIdx.x;
    __shared__ float shi[4][64];
    __shared__ float spi[4][32];
    shi[tid >> 6][tid & 63] = XH[(i0 + (tid >> 6)) * 64 + (tid & 63)];
    if (tid < 128) spi[tid >> 5][tid & 31] = XP[(i0 + (tid >> 5)) * 32 + (tid & 31)];
    __syncthreads();
    float dh[4] = {0.f, 0.f, 0.f, 0.f}, dp[4] = {0.f, 0.f, 0.f, 0.f};
#pragma unroll 16
    for (int d = 0; d < 64; ++d) {
        float v = XHT[d * NN + j];
#pragma unroll
        for (int r = 0; r < 4; ++r) { float t = v - shi[r][d]; dh[r] += t * t; }
    }
#pragma unroll 16
    for (int d = 0; d < 32; ++d) {
        float v = XPT[d * NN + j];
#pragma unroll
        for (int r = 0; r < 4; ++r) { float t = v - spi[r][d]; dp[r] += t * t; }
    }
#pragma unroll
    for (int r = 0; r < 4; ++r)
        dist[(size_t)(i0 + r) * NN + j] =
            __halves2half2(__float2half(sqrtf(dh[r])), __float2half(sqrtf(dp[r])));
    float mh = fmaxf(fmaxf(dh[0], dh[1]), fmaxf(dh[2], dh[3]));
    float mp = fmaxf(fmaxf(dp[0], dp[1]), fmaxf(dp[2], dp[3]));
#pragma unroll
    for (int m = 1; m < 64; m <<= 1) {
        mh = fmaxf(mh, __shfl_xor(mh, m));
        mp = fmaxf(mp, __shfl_xor(mp, m));
    }
    __shared__ float wmx[4][2];
    if ((tid & 63) == 0) { wmx[tid >> 6][0] = mh; wmx[tid >> 6][1] = mp; }
    __syncthreads();
    if (tid == 0) {
        float a = fmaxf(fmaxf(wmx[0][0], wmx[1][0]), fmaxf(wmx[2][0], wmx[3][0]));
        float b2 = fmaxf(fmaxf(wmx[0][1], wmx[1][1]), fmaxf(wmx[2][1], wmx[3][1]));
        atomicMax(&maxbits[0], __float_as_uint(a));
        atomicMax(&maxbits[32], __float_as_uint(b2));
    }
}

// 256 blocks x 4 waves; wave owns row i. Packed single-shuffle top-K.
__global__ __launch_bounds__(256) void gcn_topk(const __half2* __restrict__ dist,
                                                const unsigned* __restrict__ maxbits,
                                                const int* __restrict__ kptr,
                                                int* __restrict__ eidx,
                                                int* __restrict__ indeg) {
    const int tid = threadIdx.x;
    const int w = tid >> 6, lane = tid & 63;
    const int i = blockIdx.x * 4 + w;
    const float cH = -0.5f / sqrtf(__uint_as_float(maxbits[0]));
    const float cP = -1.0f / sqrtf(__uint_as_float(maxbits[32]));
    const float4* drow = (const float4*)(dist + (size_t)i * NN);
    unsigned kk[16];
#pragma unroll
    for (int s = 0; s < 4; ++s) {
        float4 v = drow[s * 64 + lane];
        const __half2* hp = (const __half2*)&v;
#pragma unroll
        for (int q = 0; q < 4; ++q) {
            float nh = __low2float(hp[q]);
            float np = __high2float(hp[q]);
            float wwv = __expf(nh * cH) + 0.2f * __expf(np * cP);
            int j = s * 256 + lane * 4 + q;
            kk[s * 4 + q] = (__float_as_uint(wwv) & 0xFFFFFC00u) | (unsigned)(1023 - j);
        }
    }
    const int K = *kptr;
    int jsave = 0;
    for (int t = 0; t < K; ++t) {
        unsigned bk = 0;
#pragma unroll
        for (int v = 0; v < 16; ++v) bk = kk[v] > bk ? kk[v] : bk;
#pragma unroll
        for (int m = 1; m < 64; m <<= 1) {
            unsigned o = (unsigned)__shfl_xor((int)bk, m);
            bk = o > bk ? o : bk;
        }
        int j = 1023 - (int)(bk & 0x3FFu);
        if (lane == t) jsave = j;
        if (((j >> 2) & 63) == lane) {
            int slot = ((j >> 8) << 2) | (j & 3);
#pragma unroll
            for (int v = 0; v < 16; ++v)
                if (v == slot) kk[v] = 0u;
        }
    }
    if (lane < K) {
        eidx[i * 16 + lane] = jsave;
        atomicAdd(&indeg[jsave], 1);
    }
}

// 16K threads: edge t of row i -> j; overlap[j] += (i in eidx[j]). eidx stale = -1.
__global__ __launch_bounds__(256) void gcn_overlap(const int* __restrict__ eidx,
                                                   int* __restrict__ overlap) {
    const int gid = blockIdx.x * 256 + threadIdx.x;
    const int i = gid >> 4;
    const int j = eidx[gid];
    if (j < 0) return;
    const int4* ej = (const int4*)(eidx + j * 16);
    bool rec = false;
#pragma unroll
    for (int q = 0; q < 4; ++q) {
        int4 e = ej[q];
        rec |= (e.x == i) | (e.y == i) | (e.z == i) | (e.w == i);
    }
    if (rec) atomicAdd(&overlap[j], 1);
}

__global__ __launch_bounds__(256) void gcn_degree(const int* __restrict__ indeg,
                                                  const int* __restrict__ overlap,
                                                  const int* __restrict__ kptr,
                                                  int* __restrict__ cdeg) {
    const int j = blockIdx.x * 256 + threadIdx.x;
    if (j < NN) cdeg[j] = *kptr + indeg[j] - overlap[j];
}

__global__ __launch_bounds__(64) void gcn_xy(const float* __restrict__ XX,
                                             const float* __restrict__ W,
                                             const float* __restrict__ psi_w,
                                             float* __restrict__ x,
                                             float* __restrict__ y) {
    const int i = blockIdx.x;
    const int e = threadIdx.x;  // 64
    __shared__ float xin[64], xs[64];
    xin[e] = XX[i * 64 + e];
    __syncthreads();
    float acc = 0.f;
#pragma unroll
    for (int d = 0; d < 64; ++d) acc += xin[d] * W[d * 64 + e];
    xs[e] = acc;
    x[i * 64 + e] = acc;
    __syncthreads();
    float acc2 = 0.f;
    const float* pw = psi_w + e * 64;
#pragma unroll
    for (int d = 0; d < 64; ++d) acc2 += xs[d] * pw[d];
    y[i * 64 + e] = acc2;
}

// One pass raw moments: m0 = S1/N^2, var = S2/N^2 - m0^2.
// S1 = sum (N+c_j) y, S2 = sum (N+3c_j) y^2.
__global__ __launch_bounds__(256) void gcn_stats(const float* __restrict__ y,
                                                 const int* __restrict__ cdeg,
                                                 const float* __restrict__ gamma,
                                                 float* __restrict__ m0out,
                                                 float* __restrict__ scaleout) {
    const int e = blockIdx.x;
    const int tid = threadIdx.x;
    __shared__ double r1[256], r2[256];
    double s1 = 0.0, s2 = 0.0;
    for (int j = tid; j < NN; j += 256) {
        double t = (double)y[j * 64 + e];
        int c = cdeg[j];
        s1 += (double)(NN + c) * t;
        s2 += (double)(NN + 3 * c) * t * t;
    }
    r1[tid] = s1; r2[tid] = s2;
    __syncthreads();
    for (int k = 128; k > 0; k >>= 1) {
        if (tid < k) { r1[tid] += r1[tid + k]; r2[tid] += r2[tid + k]; }
        __syncthreads();
    }
    if (tid == 0) {
        double m = r1[0] / 1048576.0;
        double var = r2[0] / 1048576.0 - m * m;
        m0out[e] = (float)m;
        scaleout[e] = (float)(1.0 / sqrt(var + 1e-5)) * gamma[e];
    }
}

__global__ __launch_bounds__(64) void gcn_out(const float* __restrict__ x,
                                              const float* __restrict__ y,
                                              const int* __restrict__ cdeg,
                                              const float* __restrict__ beta,
                                              const float* __restrict__ m0,
                                              const float* __restrict__ scale,
                                              const float* __restrict__ bias,
                                              const float* __restrict__ XP,
                                              float* __restrict__ out) {
    const int j = blockIdx.x;
    const int e = threadIdx.x;  // 64
    float t = y[j * 64 + e];
    float z = (2.f * t - m0[e]) * scale[e] + beta[e];
    float s = 1.f / (1.f + expf(-z));
    float val = x[j * 64 + e] * ((float)(cdeg[j] - 1) * s + 1.f) + bias[e];
    out[j * 64 + e] = val;                  // output 0: out[:, :64]
    out[98304 + j * 64 + e] = val;          // output 2: out
    if (e < 32) out[65536 + j * 32 + e] = XP[j * 32 + e];  // output 1: XP
}

extern "C" void kernel_launch(void* const* d_in, const int* in_sizes, int n_in,
                              void* d_out, int out_size, void* d_ws, size_t ws_size,
                              hipStream_t stream) {
    const float* XH    = (const float*)d_in[0];
    const float* XP    = (const float*)d_in[1];
    const float* XX    = (const float*)d_in[2];
    const int*   Kp    = (const int*)d_in[3];
    const float* W     = (const float*)d_in[4];
    const float* bias  = (const float*)d_in[5];
    const float* psi_w = (const float*)d_in[6];
    const float* psi_b = (const float*)d_in[7];
    const float* gamma = (const float*)d_in[8];
    const float* beta  = (const float*)d_in[9];
    (void)psi_b;
    float* out = (float*)d_out;
    char* ws = (char*)d_ws;

    __half2* dist     = (__half2*)ws;
    float* XHT        = (float*)(ws + 0x400000);
    float* XPT        = (float*)(ws + 0x440000);
    int* eidx         = (int*)(ws + 0x460000);
    int* indeg        = (int*)(ws + 0x470000);
    int* overlap      = (int*)(ws + 0x471000);
    unsigned* maxbits = (unsigned*)(ws + 0x472000);
    int* cdeg         = (int*)(ws + 0x473000);
    float* m0         = (float*)(ws + 0x474000);
    float* scale      = (float*)(ws + 0x474200);
    float* x          = (float*)(ws + 0x480000);
    float* y          = (float*)(ws + 0x4C0000);

    hipMemsetAsync(ws + 0x460000, 0xFF, 0x10000, stream);   // eidx = -1
    hipMemsetAsync(ws + 0x470000, 0x00, 0x3000, stream);    // indeg/overlap/maxbits

    gcn_transpose<<<dim3(16), dim3(256), 0, stream>>>(XH, XP, XHT, XPT);
    gcn_dist<<<dim3(1024), dim3(256), 0, stream>>>(XH, XP, XHT, XPT, dist, maxbits);
    gcn_topk<<<dim3(256), dim3(256), 0, stream>>>(dist, maxbits, Kp, eidx, indeg);
    gcn_overlap<<<dim3(64), dim3(256), 0, stream>>>(eidx, overlap);
    gcn_degree<<<dim3(4), dim3(256), 0, stream>>>(indeg, overlap, Kp, cdeg);
    gcn_xy<<<dim3(1024), dim3(64), 0, stream>>>(XX, W, psi_w, x, y);
    gcn_stats<<<dim3(64), dim3(256), 0, stream>>>(y, cdeg, gamma, m0, scale);
    gcn_out<<<dim3(1024), dim3(64), 0, stream>>>(x, y, cdeg, beta, m0, scale, bias, XP, out);
}